// Round 10
// baseline (1122.097 us; speedup 1.0000x reference)
//
#include <hip/hip_runtime.h>
#include <math.h>

#define NPTS 4096
#define MC   1024
#define KNB  32
#define AGT  __HIP_MEMORY_SCOPE_AGENT

typedef __attribute__((ext_vector_type(8))) short bf16x8;
typedef __attribute__((ext_vector_type(4))) float f32x4;

__device__ __forceinline__ unsigned short f2bf(float f) {
  unsigned int u = __float_as_uint(f);
  u = u + 0x7fffu + ((u >> 16) & 1u);   // round-to-nearest-even
  return (unsigned short)(u >> 16);
}

template <int CTRL>
__device__ __forceinline__ float dpp_max(float v) {
  int o = __builtin_amdgcn_update_dpp(__float_as_int(v), __float_as_int(v), CTRL, 0xF, 0xF, false);
  return fmaxf(v, __int_as_float(o));
}

// ---------------------------------------------------------------------------
// MEGA kernel. Blocks 0..15: FPS (frozen R6 formulation) streaming 16-centroid
// chunks to global + release flag. Blocks 16..1039: workers — one 16-centroid
// chunk each. Workers rel<128 first transpose 8 feature tiles each (rel<9 also
// pack weights) and publish via release fetch_add(preCnt); ALL producers live
// in the first 144 blocks so in-order dispatch guarantees they are resident —
// no consumer can starve them. Consumers: stage points -> acquire-spin on
// prog[b] -> ball query -> acquire-spin on preCnt -> MFMA MLP -> store.
// Cross-block data (cent, featsT, wpack) is published with plain stores +
// barrier + release-atomic, consumed after acquire-atomic + barrier (agent
// scope: the acquire's cache invalidate makes cross-XCD data visible).
// ---------------------------------------------------------------------------
struct FpsShared {
  float sx[NPTS], sy[NPTS], sz[NPTS];
  unsigned long long skey[2][4];
  float slog[3][MC];
};
struct TransShared { float tile[64][65]; };
struct PtsS { float sx[NPTS], sy[NPTS], sz[NPTS]; };
struct MlpS { unsigned short Hs[4][2][32 * 72]; float obuf[128 * 20]; };

__global__ __launch_bounds__(256, 1) void mega(
    const float* __restrict__ points, const float* __restrict__ feats,
    const float* __restrict__ w1, const float* __restrict__ w2,
    const float* __restrict__ w3,
    const float* __restrict__ b1, const float* __restrict__ g1, const float* __restrict__ be1,
    const float* __restrict__ b2, const float* __restrict__ g2, const float* __restrict__ be2,
    const float* __restrict__ b3, const float* __restrict__ g3, const float* __restrict__ be3,
    unsigned short* __restrict__ featsT, unsigned short* __restrict__ wpack,
    float* __restrict__ out_cent, float* __restrict__ out_feat,
    unsigned int* __restrict__ prog, unsigned int* __restrict__ preCnt) {
  __shared__ union { FpsShared f; TransShared tr; PtsS p; MlpS d; } S;
  __shared__ int lists[4][KNB];
  const int blk = blockIdx.x;
  const int t = threadIdx.x;
  const int w = t >> 6, lane = t & 63;

  if (blk < 16) {
    // ======================= FPS (frozen R6 + chunk streaming) =============
    const int b = blk;
    const float* pb = points + (size_t)b * 3 * NPTS;
    float* oc = out_cent + (size_t)b * 3 * MC;

    float fx[16], fy[16], fz[16], dist[16];
#pragma unroll
    for (int k = 0; k < 4; ++k) {
      float4 X = ((const float4*)pb)[k * 256 + t];
      float4 Y = ((const float4*)(pb + NPTS))[k * 256 + t];
      float4 Z = ((const float4*)(pb + 2 * NPTS))[k * 256 + t];
      ((float4*)S.f.sx)[k * 256 + t] = X;
      ((float4*)S.f.sy)[k * 256 + t] = Y;
      ((float4*)S.f.sz)[k * 256 + t] = Z;
      fx[k * 4 + 0] = X.x; fx[k * 4 + 1] = X.y; fx[k * 4 + 2] = X.z; fx[k * 4 + 3] = X.w;
      fy[k * 4 + 0] = Y.x; fy[k * 4 + 1] = Y.y; fy[k * 4 + 2] = Y.z; fy[k * 4 + 3] = Y.w;
      fz[k * 4 + 0] = Z.x; fz[k * 4 + 1] = Z.y; fz[k * 4 + 2] = Z.z; fz[k * 4 + 3] = Z.w;
    }
#pragma unroll
    for (int j = 0; j < 16; ++j) dist[j] = 1e10f;
    __syncthreads();

    float lx = S.f.sx[0], ly = S.f.sy[0], lz = S.f.sz[0];

    for (int i = 0; i < MC; ++i) {
      if (t == 0) { S.f.slog[0][i] = lx; S.f.slog[1][i] = ly; S.f.slog[2][i] = lz; }
      // stream finished 16-centroid chunk (wave0 only; release by lane 0)
      if ((i & 15) == 15) {
        if (t < 48) {
          const int coord = t >> 4, mm = (i & ~15) + (t & 15);
          oc[coord * MC + mm] = S.f.slog[coord][mm];
        }
        if (t == 0)
          __hip_atomic_store(&prog[b], (unsigned)(i + 1), __ATOMIC_RELEASE, AGT);
      }
      if (i == MC - 1) break;

      float m = -1.0f;
#pragma unroll
      for (int j = 0; j < 16; ++j) {
        float dx = __fsub_rn(fx[j], lx);
        float dy = __fsub_rn(fy[j], ly);
        float dz = __fsub_rn(fz[j], lz);
        float d  = __fadd_rn(__fadd_rn(__fmul_rn(dx, dx), __fmul_rn(dy, dy)), __fmul_rn(dz, dz));
        float dm = fminf(dist[j], d);
        dist[j] = dm;
        m = fmaxf(m, dm);
      }

      m = dpp_max<0x111>(m);
      m = dpp_max<0x112>(m);
      m = dpp_max<0x114>(m);
      m = dpp_max<0x118>(m);
      m = dpp_max<0x142>(m);
      m = dpp_max<0x143>(m);
      const float wv = __int_as_float(__builtin_amdgcn_readlane(__float_as_int(m), 63));

      unsigned long long mk[4][4];
#pragma unroll
      for (int k = 0; k < 4; ++k) {
        mk[k][0] = __ballot(dist[k * 4 + 0] == wv);
        mk[k][1] = __ballot(dist[k * 4 + 1] == wv);
        mk[k][2] = __ballot(dist[k * 4 + 2] == wv);
        mk[k][3] = __ballot(dist[k * 4 + 3] == wv);
      }
      unsigned long long s0 = 0, s1 = 0, s2 = 0, s3 = 0, anyk = 0;
      int sk = -1;
#pragma unroll
      for (int k = 0; k < 4; ++k) {
        unsigned long long a = mk[k][0] | mk[k][1] | mk[k][2] | mk[k][3];
        if (sk < 0 && a != 0ull) {
          sk = k; anyk = a;
          s0 = mk[k][0]; s1 = mk[k][1]; s2 = mk[k][2]; s3 = mk[k][3];
        }
      }
      const int l = __builtin_ctzll(anyk);
      const unsigned long long bit = 1ull << l;
      const int c = (s0 & bit) ? 0 : (s1 & bit) ? 1 : (s2 & bit) ? 2 : 3;
      const int selIdx = sk * 1024 + 256 * w + 4 * l + c;

      const int nb = i & 1;
      if ((t & 63) == 0)
        S.f.skey[nb][w] = ((unsigned long long)__float_as_uint(wv) << 32) | (unsigned int)~selIdx;
      __syncthreads();

      unsigned long long k0 = S.f.skey[nb][0], k1 = S.f.skey[nb][1];
      unsigned long long k2 = S.f.skey[nb][2], k3 = S.f.skey[nb][3];
      unsigned long long ka = (k0 > k1) ? k0 : k1;
      unsigned long long kb = (k2 > k3) ? k2 : k3;
      unsigned long long km = (ka > kb) ? ka : kb;
      const int sel = (int)(~(unsigned int)km);
      lx = S.f.sx[sel]; ly = S.f.sy[sel]; lz = S.f.sz[sel];
    }
    return;
  }

  // ========================== WORKER ==========================
  const int rel = blk - 16;

  // ---- producer duty: transpose (rel<128: 8 tiles) + pack (rel<9) ----
  if (rel < 128) {
    for (int j = 0; j < 8; ++j) {
      const int T = rel * 8 + j;
      const int tb = T >> 6;
      const int n0t = (T & 63) * 64;
      const float* src = feats + (size_t)tb * 64 * NPTS;
      {
        const int n = t & 63, cbase = t >> 6;
#pragma unroll
        for (int jj = 0; jj < 16; ++jj) {
          int cc = cbase + jj * 4;
          S.tr.tile[cc][n] = src[(size_t)cc * NPTS + n0t + n];
        }
      }
      __syncthreads();
      {
        const int cc = t & 63, nbase = t >> 6;
        unsigned short* dst = featsT + ((size_t)tb * NPTS + n0t) * 64;
#pragma unroll
        for (int jj = 0; jj < 16; ++jj) {
          int n = nbase + jj * 4;
          dst[(size_t)n * 64 + cc] = f2bf(S.tr.tile[cc][n]);
        }
      }
      __syncthreads();
    }
    if (rel < 9) {
      const int f = rel * 4 + w;
      if (f < 36) {
        int layer, kt, nt;
        if (f < 12)      { layer = 0; kt = f >> 2;        nt = f & 3; }
        else if (f < 20) { layer = 1; kt = (f - 12) >> 2; nt = (f - 12) & 3; }
        else             { layer = 2; kt = (f - 20) >> 3; nt = (f - 20) & 7; }
        const int o = nt * 16 + (lane & 15);
        unsigned short* dst = wpack + ((size_t)f * 64 + lane) * 8;
#pragma unroll
        for (int j = 0; j < 8; ++j) {
          int k = kt * 32 + (lane >> 4) * 8 + j;
          float x = 0.0f;
          if (layer == 0)      { if (k < 67) { int cin = (k < 64) ? (k + 3) : (k - 64); x = w1[o * 67 + cin]; } }
          else if (layer == 1) { x = w2[o * 64 + k]; }
          else                 { x = w3[o * 64 + k]; }
          dst[j] = f2bf(x);
        }
      }
    }
    __syncthreads();   // drain all waves' stores before release
    if (t == 0) {
      unsigned add = 8u + ((rel < 9) ? 4u : 0u);
      __hip_atomic_fetch_add(preCnt, add, __ATOMIC_RELEASE, AGT);
    }
  }

  const int bm0 = rel * 16;
  const int b   = bm0 >> 10;
  const int m0  = bm0 & 1023;
  const float* cbp = out_cent + (size_t)b * 3 * MC;
  const int r = lane & 15, q = lane >> 4;

  // ---- stage points (union reuse after transpose: barrier above) ----
  {
    const float* pb = points + (size_t)b * 3 * NPTS;
    __syncthreads();
#pragma unroll
    for (int j = 0; j < 4; ++j) {
      int i4 = t + j * 256;
      ((float4*)S.p.sx)[i4] = ((const float4*)pb)[i4];
      ((float4*)S.p.sy)[i4] = ((const float4*)(pb + NPTS))[i4];
      ((float4*)S.p.sz)[i4] = ((const float4*)(pb + 2 * NPTS))[i4];
    }
  }
  __syncthreads();

  // ---- wait for our centroid chunk ----
  if (t == 0) {
    while (__hip_atomic_load(&prog[b], __ATOMIC_ACQUIRE, AGT) < (unsigned)(m0 + 16))
      __builtin_amdgcn_s_sleep(16);
  }
  __syncthreads();

  // ---- ball query for this wave's 4 centroids (R8-proven) ----
  int n0r[4], n1r[4];
  bf16x8 aL[4][2];
  const float R2 = (float)(0.2 * 0.2);
#pragma unroll
  for (int it = 0; it < 4; ++it) {
    const int m = m0 + it * 4 + w;
    const float cx = cbp[m], cy = cbp[MC + m], cz = cbp[2 * MC + m];
    const float c2 = __fadd_rn(__fadd_rn(__fmul_rn(cx, cx), __fmul_rn(cy, cy)), __fmul_rn(cz, cz));
    int cnt = 0;
    for (int ch = 0; ch < 64; ++ch) {
      const int n = ch * 64 + lane;
      float x = S.p.sx[n], y = S.p.sy[n], z = S.p.sz[n];
      float p2  = __fadd_rn(__fadd_rn(__fmul_rn(x, x),  __fmul_rn(y, y)),  __fmul_rn(z, z));
      float dot = __fadd_rn(__fadd_rn(__fmul_rn(cx, x), __fmul_rn(cy, y)), __fmul_rn(cz, z));
      float d2  = __fsub_rn(__fadd_rn(c2, p2), __fmul_rn(2.0f, dot));
      bool hit = (d2 <= R2);
      unsigned long long msk = __ballot(hit);
      if (hit) {
        int pos = cnt + __popcll(msk & ((1ull << lane) - 1ull));
        if (pos < KNB) lists[w][pos] = n;
      }
      cnt += __popcll(msk);
      if (cnt >= KNB) break;
    }
    {
      int first = lists[w][0];
      if (lane < KNB) {
        int v = (lane < cnt) ? lists[w][lane] : first;
        lists[w][lane] = v;
      }
    }
    const int n0 = lists[w][r];
    const int n1 = lists[w][16 + r];
    n0r[it] = n0; n1r[it] = n1;
#pragma unroll
    for (int mt = 0; mt < 2; ++mt) {
      bf16x8 a = {0, 0, 0, 0, 0, 0, 0, 0};
      if (q == 0) {
        int n = mt ? n1 : n0;
        a[0] = (short)f2bf(S.p.sx[n] - cx);
        a[1] = (short)f2bf(S.p.sy[n] - cy);
        a[2] = (short)f2bf(S.p.sz[n] - cz);
      }
      aL[it][mt] = a;
    }
  }
  __syncthreads();   // done with points LDS; reuse for Hs/obuf

  // ---- wait for featsT + wpack producers ----
  if (t == 0) {
    while (__hip_atomic_load(preCnt, __ATOMIC_ACQUIRE, AGT) < 1060u)
      __builtin_amdgcn_s_sleep(16);
  }
  __syncthreads();

  // ---- epilogue constants ----
  const float inv_s = 1.0f / sqrtf(1.0f + 1e-5f);
  float pb1[4], ps1[4], pe1[4], pb2[4], ps2[4], pe2[4], pb3[8], ps3[8], pe3[8];
#pragma unroll
  for (int nt = 0; nt < 4; ++nt) {
    int o = nt * 16 + r;
    pb1[nt] = b1[o]; ps1[nt] = g1[o] * inv_s; pe1[nt] = be1[o];
    pb2[nt] = b2[o]; ps2[nt] = g2[o] * inv_s; pe2[nt] = be2[o];
  }
#pragma unroll
  for (int nt = 0; nt < 8; ++nt) {
    int o = nt * 16 + r;
    pb3[nt] = b3[o]; ps3[nt] = g3[o] * inv_s; pe3[nt] = be3[o];
  }

  // ---- MLP (R8-proven) ----
  for (int it = 0; it < 4; ++it) {
    const int ml = it * 4 + w;
    const int n0 = n0r[it], n1 = n1r[it];

    bf16x8 aF[2][2];
#pragma unroll
    for (int mt = 0; mt < 2; ++mt) {
      int n = mt ? n1 : n0;
      const unsigned short* rowp = featsT + ((size_t)b * NPTS + n) * 64 + q * 8;
      aF[mt][0] = *(const bf16x8*)(rowp);
      aF[mt][1] = *(const bf16x8*)(rowp + 32);
    }
    f32x4 acc1[2][4];
#pragma unroll
    for (int mt = 0; mt < 2; ++mt)
#pragma unroll
      for (int nt = 0; nt < 4; ++nt) acc1[mt][nt] = (f32x4){0.f, 0.f, 0.f, 0.f};
#pragma unroll
    for (int kt = 0; kt < 3; ++kt) {
#pragma unroll
      for (int nt = 0; nt < 4; ++nt) {
        bf16x8 wf = *(const bf16x8*)(wpack + ((size_t)(kt * 4 + nt) * 64 + lane) * 8);
#pragma unroll
        for (int mt = 0; mt < 2; ++mt) {
          bf16x8 a = (kt < 2) ? aF[mt][kt] : aL[it][mt];
          acc1[mt][nt] = __builtin_amdgcn_mfma_f32_16x16x32_bf16(a, wf, acc1[mt][nt], 0, 0, 0);
        }
      }
    }
#pragma unroll
    for (int mt = 0; mt < 2; ++mt)
#pragma unroll
      for (int nt = 0; nt < 4; ++nt)
#pragma unroll
        for (int rr = 0; rr < 4; ++rr) {
          float y = (acc1[mt][nt][rr] + pb1[nt]) * ps1[nt] + pe1[nt];
          y = fmaxf(y, 0.0f);
          S.d.Hs[w][0][(mt * 16 + q * 4 + rr) * 72 + nt * 16 + r] = f2bf(y);
        }
    __threadfence_block();

    f32x4 acc2[2][4];
#pragma unroll
    for (int mt = 0; mt < 2; ++mt)
#pragma unroll
      for (int nt = 0; nt < 4; ++nt) acc2[mt][nt] = (f32x4){0.f, 0.f, 0.f, 0.f};
#pragma unroll
    for (int kt = 0; kt < 2; ++kt) {
      bf16x8 a0 = *(const bf16x8*)&S.d.Hs[w][0][(0 * 16 + r) * 72 + kt * 32 + q * 8];
      bf16x8 a1 = *(const bf16x8*)&S.d.Hs[w][0][(1 * 16 + r) * 72 + kt * 32 + q * 8];
#pragma unroll
      for (int nt = 0; nt < 4; ++nt) {
        bf16x8 wf = *(const bf16x8*)(wpack + ((size_t)(12 + kt * 4 + nt) * 64 + lane) * 8);
        acc2[0][nt] = __builtin_amdgcn_mfma_f32_16x16x32_bf16(a0, wf, acc2[0][nt], 0, 0, 0);
        acc2[1][nt] = __builtin_amdgcn_mfma_f32_16x16x32_bf16(a1, wf, acc2[1][nt], 0, 0, 0);
      }
    }
#pragma unroll
    for (int mt = 0; mt < 2; ++mt)
#pragma unroll
      for (int nt = 0; nt < 4; ++nt)
#pragma unroll
        for (int rr = 0; rr < 4; ++rr) {
          float y = (acc2[mt][nt][rr] + pb2[nt]) * ps2[nt] + pe2[nt];
          y = fmaxf(y, 0.0f);
          S.d.Hs[w][1][(mt * 16 + q * 4 + rr) * 72 + nt * 16 + r] = f2bf(y);
        }
    __threadfence_block();

    f32x4 acc3[2][8];
#pragma unroll
    for (int mt = 0; mt < 2; ++mt)
#pragma unroll
      for (int nt = 0; nt < 8; ++nt) acc3[mt][nt] = (f32x4){0.f, 0.f, 0.f, 0.f};
#pragma unroll
    for (int kt = 0; kt < 2; ++kt) {
      bf16x8 a0 = *(const bf16x8*)&S.d.Hs[w][1][(0 * 16 + r) * 72 + kt * 32 + q * 8];
      bf16x8 a1 = *(const bf16x8*)&S.d.Hs[w][1][(1 * 16 + r) * 72 + kt * 32 + q * 8];
#pragma unroll
      for (int nt = 0; nt < 8; ++nt) {
        bf16x8 wf = *(const bf16x8*)(wpack + ((size_t)(20 + kt * 8 + nt) * 64 + lane) * 8);
        acc3[0][nt] = __builtin_amdgcn_mfma_f32_16x16x32_bf16(a0, wf, acc3[0][nt], 0, 0, 0);
        acc3[1][nt] = __builtin_amdgcn_mfma_f32_16x16x32_bf16(a1, wf, acc3[1][nt], 0, 0, 0);
      }
    }
#pragma unroll
    for (int nt = 0; nt < 8; ++nt) {
      float pm = 0.0f;
#pragma unroll
      for (int mt = 0; mt < 2; ++mt)
#pragma unroll
        for (int rr = 0; rr < 4; ++rr) {
          float y = (acc3[mt][nt][rr] + pb3[nt]) * ps3[nt] + pe3[nt];
          y = fmaxf(y, 0.0f);
          pm = fmaxf(pm, y);
        }
      pm = fmaxf(pm, __shfl_xor(pm, 16));
      pm = fmaxf(pm, __shfl_xor(pm, 32));
      if (q == 0) S.d.obuf[(nt * 16 + r) * 20 + ml] = pm;
    }
    __threadfence_block();
  }
  __syncthreads();
  {
    const int ch = t >> 1, mh = (t & 1) * 8;
    float4 u0 = *(const float4*)&S.d.obuf[ch * 20 + mh];
    float4 u1 = *(const float4*)&S.d.obuf[ch * 20 + mh + 4];
    float* outp = out_feat + ((size_t)b * 128 + ch) * 1024 + m0 + mh;
    *(float4*)(outp)     = u0;
    *(float4*)(outp + 4) = u1;
  }
}

// ---------------------------------------------------------------------------
extern "C" void kernel_launch(void* const* d_in, const int* in_sizes, int n_in,
                              void* d_out, int out_size, void* d_ws, size_t ws_size,
                              hipStream_t stream) {
  (void)in_sizes; (void)n_in; (void)out_size; (void)ws_size;
  const float* points   = (const float*)d_in[0];
  const float* features = (const float*)d_in[1];
  const float* w1  = (const float*)d_in[2];
  const float* b1  = (const float*)d_in[3];
  const float* g1  = (const float*)d_in[4];
  const float* be1 = (const float*)d_in[5];
  const float* w2  = (const float*)d_in[6];
  const float* b2  = (const float*)d_in[7];
  const float* g2  = (const float*)d_in[8];
  const float* be2 = (const float*)d_in[9];
  const float* w3  = (const float*)d_in[10];
  const float* b3  = (const float*)d_in[11];
  const float* g3  = (const float*)d_in[12];
  const float* be3 = (const float*)d_in[13];

  float* outc = (float*)d_out;                  // centroids [16,3,1024]
  float* outf = outc + 16 * 3 * 1024;           // features  [16,128,1024]

  char* ws = (char*)d_ws;
  unsigned short* featsT = (unsigned short*)(ws);            // 8 MiB
  unsigned short* wpack  = (unsigned short*)(ws + 0x800000); // 36 KiB
  unsigned int*   prog   = (unsigned int*)(ws + 0x810000);   // 16 uints
  unsigned int*   preCnt = (unsigned int*)(ws + 0x810040);   // 1 uint

  hipMemsetAsync(ws + 0x810000, 0, 0x80, stream);
  mega<<<16 + 1024, 256, 0, stream>>>(points, features, w1, w2, w3,
                                      b1, g1, be1, b2, g2, be2, b3, g3, be3,
                                      featsT, wpack, outc, outf, prog, preCnt);
}

// Round 11
// 1102.736 us; speedup vs baseline: 1.0176x; 1.0176x over previous
//
#include <hip/hip_runtime.h>
#include <math.h>

#define NPTS 4096
#define MC   1024
#define KNB  32
#define AGT  __HIP_MEMORY_SCOPE_AGENT

typedef __attribute__((ext_vector_type(8))) short bf16x8;
typedef __attribute__((ext_vector_type(4))) float f32x4;

__device__ __forceinline__ unsigned short f2bf(float f) {
  unsigned int u = __float_as_uint(f);
  u = u + 0x7fffu + ((u >> 16) & 1u);   // round-to-nearest-even
  return (unsigned short)(u >> 16);
}

template <int CTRL>
__device__ __forceinline__ float dpp_max(float v) {
  int o = __builtin_amdgcn_update_dpp(__float_as_int(v), __float_as_int(v), CTRL, 0xF, 0xF, false);
  return fmaxf(v, __int_as_float(o));
}

// ---------------------------------------------------------------------------
// MEGA kernel, R11: R10's producer/consumer streaming + FPS ISOLATION.
// The shared union is padded to 86 KB so LDS allows only ONE block per CU:
// the 16 FPS blocks own their CUs (R10's 2-blocks/CU co-residency stretched
// FPS 1.49x via issue-slot + DS-pipe contention: VALUBusy 2.8->8.9%,
// LDS conflicts 6k->1.26M). Workers get the other 240 CUs.
// Blocks 0..15: FPS (frozen R6 math) streaming 16-centroid chunks + release
// flag. Blocks 16..1039: workers (one 16-centroid chunk each); rel<128 also
// produce featsT (8 tiles each), rel<9 produce wpack; all producers sit in
// the first 144 worker blocks => resident under in-order dispatch.
// ---------------------------------------------------------------------------
struct FpsShared {
  float sx[NPTS], sy[NPTS], sz[NPTS];
  unsigned long long skey[2][4];
  float slog[3][MC];
};
struct TransShared { float tile[64][65]; };
struct PtsS { float sx[NPTS], sy[NPTS], sz[NPTS]; };
struct MlpS { unsigned short Hs[4][2][32 * 72]; float obuf[128 * 20]; };

__global__ __launch_bounds__(256, 1) void mega(
    const float* __restrict__ points, const float* __restrict__ feats,
    const float* __restrict__ w1, const float* __restrict__ w2,
    const float* __restrict__ w3,
    const float* __restrict__ b1, const float* __restrict__ g1, const float* __restrict__ be1,
    const float* __restrict__ b2, const float* __restrict__ g2, const float* __restrict__ be2,
    const float* __restrict__ b3, const float* __restrict__ g3, const float* __restrict__ be3,
    unsigned short* __restrict__ featsT, unsigned short* __restrict__ wpack,
    float* __restrict__ out_cent, float* __restrict__ out_feat,
    unsigned int* __restrict__ prog, unsigned int* __restrict__ preCnt) {
  __shared__ union {
    FpsShared f; TransShared tr; PtsS p; MlpS d;
    char occupancy_pad[86 * 1024];   // force 1 block/CU: isolate FPS CUs
  } S;
  __shared__ int lists[4][KNB];
  const int blk = blockIdx.x;
  const int t = threadIdx.x;
  const int w = t >> 6, lane = t & 63;

  if (blk < 16) {
    // ======================= FPS (frozen R6 + chunk streaming) =============
    __builtin_amdgcn_s_setprio(3);   // protect the latency-critical chain
    const int b = blk;
    const float* pb = points + (size_t)b * 3 * NPTS;
    float* oc = out_cent + (size_t)b * 3 * MC;

    float fx[16], fy[16], fz[16], dist[16];
#pragma unroll
    for (int k = 0; k < 4; ++k) {
      float4 X = ((const float4*)pb)[k * 256 + t];
      float4 Y = ((const float4*)(pb + NPTS))[k * 256 + t];
      float4 Z = ((const float4*)(pb + 2 * NPTS))[k * 256 + t];
      ((float4*)S.f.sx)[k * 256 + t] = X;
      ((float4*)S.f.sy)[k * 256 + t] = Y;
      ((float4*)S.f.sz)[k * 256 + t] = Z;
      fx[k * 4 + 0] = X.x; fx[k * 4 + 1] = X.y; fx[k * 4 + 2] = X.z; fx[k * 4 + 3] = X.w;
      fy[k * 4 + 0] = Y.x; fy[k * 4 + 1] = Y.y; fy[k * 4 + 2] = Y.z; fy[k * 4 + 3] = Y.w;
      fz[k * 4 + 0] = Z.x; fz[k * 4 + 1] = Z.y; fz[k * 4 + 2] = Z.z; fz[k * 4 + 3] = Z.w;
    }
#pragma unroll
    for (int j = 0; j < 16; ++j) dist[j] = 1e10f;
    __syncthreads();

    float lx = S.f.sx[0], ly = S.f.sy[0], lz = S.f.sz[0];

    for (int i = 0; i < MC; ++i) {
      if (t == 0) { S.f.slog[0][i] = lx; S.f.slog[1][i] = ly; S.f.slog[2][i] = lz; }
      // stream finished 16-centroid chunk (wave0; release by lane 0)
      if ((i & 15) == 15) {
        if (t < 48) {
          const int coord = t >> 4, mm = (i & ~15) + (t & 15);
          oc[coord * MC + mm] = S.f.slog[coord][mm];
        }
        if (t == 0)
          __hip_atomic_store(&prog[b], (unsigned)(i + 1), __ATOMIC_RELEASE, AGT);
      }
      if (i == MC - 1) break;

      float m = -1.0f;
#pragma unroll
      for (int j = 0; j < 16; ++j) {
        float dx = __fsub_rn(fx[j], lx);
        float dy = __fsub_rn(fy[j], ly);
        float dz = __fsub_rn(fz[j], lz);
        float d  = __fadd_rn(__fadd_rn(__fmul_rn(dx, dx), __fmul_rn(dy, dy)), __fmul_rn(dz, dz));
        float dm = fminf(dist[j], d);
        dist[j] = dm;
        m = fmaxf(m, dm);
      }

      m = dpp_max<0x111>(m);
      m = dpp_max<0x112>(m);
      m = dpp_max<0x114>(m);
      m = dpp_max<0x118>(m);
      m = dpp_max<0x142>(m);
      m = dpp_max<0x143>(m);
      const float wv = __int_as_float(__builtin_amdgcn_readlane(__float_as_int(m), 63));

      unsigned long long mk[4][4];
#pragma unroll
      for (int k = 0; k < 4; ++k) {
        mk[k][0] = __ballot(dist[k * 4 + 0] == wv);
        mk[k][1] = __ballot(dist[k * 4 + 1] == wv);
        mk[k][2] = __ballot(dist[k * 4 + 2] == wv);
        mk[k][3] = __ballot(dist[k * 4 + 3] == wv);
      }
      unsigned long long s0 = 0, s1 = 0, s2 = 0, s3 = 0, anyk = 0;
      int sk = -1;
#pragma unroll
      for (int k = 0; k < 4; ++k) {
        unsigned long long a = mk[k][0] | mk[k][1] | mk[k][2] | mk[k][3];
        if (sk < 0 && a != 0ull) {
          sk = k; anyk = a;
          s0 = mk[k][0]; s1 = mk[k][1]; s2 = mk[k][2]; s3 = mk[k][3];
        }
      }
      const int l = __builtin_ctzll(anyk);
      const unsigned long long bit = 1ull << l;
      const int c = (s0 & bit) ? 0 : (s1 & bit) ? 1 : (s2 & bit) ? 2 : 3;
      const int selIdx = sk * 1024 + 256 * w + 4 * l + c;

      const int nb = i & 1;
      if ((t & 63) == 0)
        S.f.skey[nb][w] = ((unsigned long long)__float_as_uint(wv) << 32) | (unsigned int)~selIdx;
      __syncthreads();

      unsigned long long k0 = S.f.skey[nb][0], k1 = S.f.skey[nb][1];
      unsigned long long k2 = S.f.skey[nb][2], k3 = S.f.skey[nb][3];
      unsigned long long ka = (k0 > k1) ? k0 : k1;
      unsigned long long kb = (k2 > k3) ? k2 : k3;
      unsigned long long km = (ka > kb) ? ka : kb;
      const int sel = (int)(~(unsigned int)km);
      lx = S.f.sx[sel]; ly = S.f.sy[sel]; lz = S.f.sz[sel];
    }
    return;
  }

  // ========================== WORKER ==========================
  const int rel = blk - 16;

  // ---- producer duty: transpose (rel<128: 8 tiles) + pack (rel<9) ----
  if (rel < 128) {
    for (int j = 0; j < 8; ++j) {
      const int T = rel * 8 + j;
      const int tb = T >> 6;
      const int n0t = (T & 63) * 64;
      const float* src = feats + (size_t)tb * 64 * NPTS;
      {
        const int n = t & 63, cbase = t >> 6;
#pragma unroll
        for (int jj = 0; jj < 16; ++jj) {
          int cc = cbase + jj * 4;
          S.tr.tile[cc][n] = src[(size_t)cc * NPTS + n0t + n];
        }
      }
      __syncthreads();
      {
        const int cc = t & 63, nbase = t >> 6;
        unsigned short* dst = featsT + ((size_t)tb * NPTS + n0t) * 64;
#pragma unroll
        for (int jj = 0; jj < 16; ++jj) {
          int n = nbase + jj * 4;
          dst[(size_t)n * 64 + cc] = f2bf(S.tr.tile[cc][n]);
        }
      }
      __syncthreads();
    }
    if (rel < 9) {
      const int f = rel * 4 + w;
      if (f < 36) {
        int layer, kt, nt;
        if (f < 12)      { layer = 0; kt = f >> 2;        nt = f & 3; }
        else if (f < 20) { layer = 1; kt = (f - 12) >> 2; nt = (f - 12) & 3; }
        else             { layer = 2; kt = (f - 20) >> 3; nt = (f - 20) & 7; }
        const int o = nt * 16 + (lane & 15);
        unsigned short* dst = wpack + ((size_t)f * 64 + lane) * 8;
#pragma unroll
        for (int j = 0; j < 8; ++j) {
          int k = kt * 32 + (lane >> 4) * 8 + j;
          float x = 0.0f;
          if (layer == 0)      { if (k < 67) { int cin = (k < 64) ? (k + 3) : (k - 64); x = w1[o * 67 + cin]; } }
          else if (layer == 1) { x = w2[o * 64 + k]; }
          else                 { x = w3[o * 64 + k]; }
          dst[j] = f2bf(x);
        }
      }
    }
    __syncthreads();   // drain all waves' stores before release
    if (t == 0) {
      unsigned add = 8u + ((rel < 9) ? 4u : 0u);
      __hip_atomic_fetch_add(preCnt, add, __ATOMIC_RELEASE, AGT);
    }
  }

  const int bm0 = rel * 16;
  const int b   = bm0 >> 10;
  const int m0  = bm0 & 1023;
  const float* cbp = out_cent + (size_t)b * 3 * MC;
  const int r = lane & 15, q = lane >> 4;

  // ---- stage points (union reuse after transpose: barrier above) ----
  {
    const float* pb = points + (size_t)b * 3 * NPTS;
    __syncthreads();
#pragma unroll
    for (int j = 0; j < 4; ++j) {
      int i4 = t + j * 256;
      ((float4*)S.p.sx)[i4] = ((const float4*)pb)[i4];
      ((float4*)S.p.sy)[i4] = ((const float4*)(pb + NPTS))[i4];
      ((float4*)S.p.sz)[i4] = ((const float4*)(pb + 2 * NPTS))[i4];
    }
  }
  __syncthreads();

  // ---- wait for our centroid chunk ----
  if (t == 0) {
    while (__hip_atomic_load(&prog[b], __ATOMIC_ACQUIRE, AGT) < (unsigned)(m0 + 16))
      __builtin_amdgcn_s_sleep(64);
  }
  __syncthreads();

  // ---- ball query for this wave's 4 centroids ----
  int n0r[4], n1r[4];
  bf16x8 aL[4][2];
  const float R2 = (float)(0.2 * 0.2);
#pragma unroll
  for (int it = 0; it < 4; ++it) {
    const int m = m0 + it * 4 + w;
    const float cx = cbp[m], cy = cbp[MC + m], cz = cbp[2 * MC + m];
    const float c2 = __fadd_rn(__fadd_rn(__fmul_rn(cx, cx), __fmul_rn(cy, cy)), __fmul_rn(cz, cz));
    int cnt = 0;
    for (int ch = 0; ch < 64; ++ch) {
      const int n = ch * 64 + lane;
      float x = S.p.sx[n], y = S.p.sy[n], z = S.p.sz[n];
      float p2  = __fadd_rn(__fadd_rn(__fmul_rn(x, x),  __fmul_rn(y, y)),  __fmul_rn(z, z));
      float dot = __fadd_rn(__fadd_rn(__fmul_rn(cx, x), __fmul_rn(cy, y)), __fmul_rn(cz, z));
      float d2  = __fsub_rn(__fadd_rn(c2, p2), __fmul_rn(2.0f, dot));
      bool hit = (d2 <= R2);
      unsigned long long msk = __ballot(hit);
      if (hit) {
        int pos = cnt + __popcll(msk & ((1ull << lane) - 1ull));
        if (pos < KNB) lists[w][pos] = n;
      }
      cnt += __popcll(msk);
      if (cnt >= KNB) break;
    }
    {
      int first = lists[w][0];
      if (lane < KNB) {
        int v = (lane < cnt) ? lists[w][lane] : first;
        lists[w][lane] = v;
      }
    }
    const int n0 = lists[w][r];
    const int n1 = lists[w][16 + r];
    n0r[it] = n0; n1r[it] = n1;
#pragma unroll
    for (int mt = 0; mt < 2; ++mt) {
      bf16x8 a = {0, 0, 0, 0, 0, 0, 0, 0};
      if (q == 0) {
        int n = mt ? n1 : n0;
        a[0] = (short)f2bf(S.p.sx[n] - cx);
        a[1] = (short)f2bf(S.p.sy[n] - cy);
        a[2] = (short)f2bf(S.p.sz[n] - cz);
      }
      aL[it][mt] = a;
    }
  }
  __syncthreads();   // done with points LDS; reuse for Hs/obuf

  // ---- wait for featsT + wpack producers ----
  if (t == 0) {
    while (__hip_atomic_load(preCnt, __ATOMIC_ACQUIRE, AGT) < 1060u)
      __builtin_amdgcn_s_sleep(64);
  }
  __syncthreads();

  // ---- epilogue constants ----
  const float inv_s = 1.0f / sqrtf(1.0f + 1e-5f);
  float pb1[4], ps1[4], pe1[4], pb2[4], ps2[4], pe2[4], pb3[8], ps3[8], pe3[8];
#pragma unroll
  for (int nt = 0; nt < 4; ++nt) {
    int o = nt * 16 + r;
    pb1[nt] = b1[o]; ps1[nt] = g1[o] * inv_s; pe1[nt] = be1[o];
    pb2[nt] = b2[o]; ps2[nt] = g2[o] * inv_s; pe2[nt] = be2[o];
  }
#pragma unroll
  for (int nt = 0; nt < 8; ++nt) {
    int o = nt * 16 + r;
    pb3[nt] = b3[o]; ps3[nt] = g3[o] * inv_s; pe3[nt] = be3[o];
  }

  // ---- MLP ----
  for (int it = 0; it < 4; ++it) {
    const int ml = it * 4 + w;
    const int n0 = n0r[it], n1 = n1r[it];

    bf16x8 aF[2][2];
#pragma unroll
    for (int mt = 0; mt < 2; ++mt) {
      int n = mt ? n1 : n0;
      const unsigned short* rowp = featsT + ((size_t)b * NPTS + n) * 64 + q * 8;
      aF[mt][0] = *(const bf16x8*)(rowp);
      aF[mt][1] = *(const bf16x8*)(rowp + 32);
    }
    f32x4 acc1[2][4];
#pragma unroll
    for (int mt = 0; mt < 2; ++mt)
#pragma unroll
      for (int nt = 0; nt < 4; ++nt) acc1[mt][nt] = (f32x4){0.f, 0.f, 0.f, 0.f};
#pragma unroll
    for (int kt = 0; kt < 3; ++kt) {
#pragma unroll
      for (int nt = 0; nt < 4; ++nt) {
        bf16x8 wf = *(const bf16x8*)(wpack + ((size_t)(kt * 4 + nt) * 64 + lane) * 8);
#pragma unroll
        for (int mt = 0; mt < 2; ++mt) {
          bf16x8 a = (kt < 2) ? aF[mt][kt] : aL[it][mt];
          acc1[mt][nt] = __builtin_amdgcn_mfma_f32_16x16x32_bf16(a, wf, acc1[mt][nt], 0, 0, 0);
        }
      }
    }
#pragma unroll
    for (int mt = 0; mt < 2; ++mt)
#pragma unroll
      for (int nt = 0; nt < 4; ++nt)
#pragma unroll
        for (int rr = 0; rr < 4; ++rr) {
          float y = (acc1[mt][nt][rr] + pb1[nt]) * ps1[nt] + pe1[nt];
          y = fmaxf(y, 0.0f);
          S.d.Hs[w][0][(mt * 16 + q * 4 + rr) * 72 + nt * 16 + r] = f2bf(y);
        }
    __threadfence_block();

    f32x4 acc2[2][4];
#pragma unroll
    for (int mt = 0; mt < 2; ++mt)
#pragma unroll
      for (int nt = 0; nt < 4; ++nt) acc2[mt][nt] = (f32x4){0.f, 0.f, 0.f, 0.f};
#pragma unroll
    for (int kt = 0; kt < 2; ++kt) {
      bf16x8 a0 = *(const bf16x8*)&S.d.Hs[w][0][(0 * 16 + r) * 72 + kt * 32 + q * 8];
      bf16x8 a1 = *(const bf16x8*)&S.d.Hs[w][0][(1 * 16 + r) * 72 + kt * 32 + q * 8];
#pragma unroll
      for (int nt = 0; nt < 4; ++nt) {
        bf16x8 wf = *(const bf16x8*)(wpack + ((size_t)(12 + kt * 4 + nt) * 64 + lane) * 8);
        acc2[0][nt] = __builtin_amdgcn_mfma_f32_16x16x32_bf16(a0, wf, acc2[0][nt], 0, 0, 0);
        acc2[1][nt] = __builtin_amdgcn_mfma_f32_16x16x32_bf16(a1, wf, acc2[1][nt], 0, 0, 0);
      }
    }
#pragma unroll
    for (int mt = 0; mt < 2; ++mt)
#pragma unroll
      for (int nt = 0; nt < 4; ++nt)
#pragma unroll
        for (int rr = 0; rr < 4; ++rr) {
          float y = (acc2[mt][nt][rr] + pb2[nt]) * ps2[nt] + pe2[nt];
          y = fmaxf(y, 0.0f);
          S.d.Hs[w][1][(mt * 16 + q * 4 + rr) * 72 + nt * 16 + r] = f2bf(y);
        }
    __threadfence_block();

    f32x4 acc3[2][8];
#pragma unroll
    for (int mt = 0; mt < 2; ++mt)
#pragma unroll
      for (int nt = 0; nt < 8; ++nt) acc3[mt][nt] = (f32x4){0.f, 0.f, 0.f, 0.f};
#pragma unroll
    for (int kt = 0; kt < 2; ++kt) {
      bf16x8 a0 = *(const bf16x8*)&S.d.Hs[w][1][(0 * 16 + r) * 72 + kt * 32 + q * 8];
      bf16x8 a1 = *(const bf16x8*)&S.d.Hs[w][1][(1 * 16 + r) * 72 + kt * 32 + q * 8];
#pragma unroll
      for (int nt = 0; nt < 8; ++nt) {
        bf16x8 wf = *(const bf16x8*)(wpack + ((size_t)(20 + kt * 8 + nt) * 64 + lane) * 8);
        acc3[0][nt] = __builtin_amdgcn_mfma_f32_16x16x32_bf16(a0, wf, acc3[0][nt], 0, 0, 0);
        acc3[1][nt] = __builtin_amdgcn_mfma_f32_16x16x32_bf16(a1, wf, acc3[1][nt], 0, 0, 0);
      }
    }
#pragma unroll
    for (int nt = 0; nt < 8; ++nt) {
      float pm = 0.0f;
#pragma unroll
      for (int mt = 0; mt < 2; ++mt)
#pragma unroll
        for (int rr = 0; rr < 4; ++rr) {
          float y = (acc3[mt][nt][rr] + pb3[nt]) * ps3[nt] + pe3[nt];
          y = fmaxf(y, 0.0f);
          pm = fmaxf(pm, y);
        }
      pm = fmaxf(pm, __shfl_xor(pm, 16));
      pm = fmaxf(pm, __shfl_xor(pm, 32));
      if (q == 0) S.d.obuf[(nt * 16 + r) * 20 + ml] = pm;
    }
    __threadfence_block();
  }
  __syncthreads();
  {
    const int ch = t >> 1, mh = (t & 1) * 8;
    float4 u0 = *(const float4*)&S.d.obuf[ch * 20 + mh];
    float4 u1 = *(const float4*)&S.d.obuf[ch * 20 + mh + 4];
    float* outp = out_feat + ((size_t)b * 128 + ch) * 1024 + m0 + mh;
    *(float4*)(outp)     = u0;
    *(float4*)(outp + 4) = u1;
  }
}

// ---------------------------------------------------------------------------
extern "C" void kernel_launch(void* const* d_in, const int* in_sizes, int n_in,
                              void* d_out, int out_size, void* d_ws, size_t ws_size,
                              hipStream_t stream) {
  (void)in_sizes; (void)n_in; (void)out_size; (void)ws_size;
  const float* points   = (const float*)d_in[0];
  const float* features = (const float*)d_in[1];
  const float* w1  = (const float*)d_in[2];
  const float* b1  = (const float*)d_in[3];
  const float* g1  = (const float*)d_in[4];
  const float* be1 = (const float*)d_in[5];
  const float* w2  = (const float*)d_in[6];
  const float* b2  = (const float*)d_in[7];
  const float* g2  = (const float*)d_in[8];
  const float* be2 = (const float*)d_in[9];
  const float* w3  = (const float*)d_in[10];
  const float* b3  = (const float*)d_in[11];
  const float* g3  = (const float*)d_in[12];
  const float* be3 = (const float*)d_in[13];

  float* outc = (float*)d_out;                  // centroids [16,3,1024]
  float* outf = outc + 16 * 3 * 1024;           // features  [16,128,1024]

  char* ws = (char*)d_ws;
  unsigned short* featsT = (unsigned short*)(ws);            // 8 MiB
  unsigned short* wpack  = (unsigned short*)(ws + 0x800000); // 36 KiB
  unsigned int*   prog   = (unsigned int*)(ws + 0x810000);   // 16 uints
  unsigned int*   preCnt = (unsigned int*)(ws + 0x810040);   // 1 uint

  hipMemsetAsync(ws + 0x810000, 0, 0x80, stream);
  mega<<<16 + 1024, 256, 0, stream>>>(points, features, w1, w2, w3,
                                      b1, g1, be1, b2, g2, be2, b3, g3, be3,
                                      featsT, wpack, outc, outf, prog, preCnt);
}